// Round 5
// baseline (195.175 us; speedup 1.0000x reference)
//
#include <hip/hip_runtime.h>
#include <hip/hip_bf16.h>

// Problem: B=4, C=8, N=M=K=1024, DX=1.
// z1[b,c] = W_b (N x M) @ Z_{b,c} (M x K);  z2[b,c] = z1 @ z1^T
// W[b][n][m] = exp(-512 * (x[b][n] - xz[m])^2)
// d_out = [ xz (1024 f32) | z2 (4*8*1024*1024 f32) ]
// ws: W bf16 (8 MB) | Zt bf16 (64 MB, [b][c][k][m]) | z1 bf16 (64 MB, [b][c][n][k])
//
// GEMM: 256x256 tile, BK=64, 512 thr (8 waves 2Mx4N, wave-tile 128x64),
// 8-phase-style schedule: 4 phases/tile (C-quadrant = (m-sub,k-half), 16 MFMA),
// one half-tile (16KB, 2xGLDS) staged per phase with >=2-phase lead,
// counted vmcnt(8) twice per tile (drain-peeled 4/0 at the end), setprio
// around MFMA. LDS layout [buf][khalf][row][32k] -> 64B rows =
// conflict-free ds_read_b128 AND linear global_load_lds dest (no swizzle).

typedef __attribute__((ext_vector_type(8))) unsigned short u16x8;
typedef __attribute__((ext_vector_type(8))) __bf16 bf16x8;
typedef __attribute__((ext_vector_type(4))) float f32x4;

typedef __attribute__((address_space(1))) void gvoid;
typedef __attribute__((address_space(3))) void svoid;
#define GLDS(g, s) __builtin_amdgcn_global_load_lds((gvoid*)(g), (svoid*)(s), 16, 0, 0)
#define BAR() asm volatile("s_barrier" ::: "memory")

__device__ __forceinline__ unsigned short f2bf(float f) {
  unsigned int u = __builtin_bit_cast(unsigned int, f);
  u += 0x7fffu + ((u >> 16) & 1u);   // round-to-nearest-even
  return (unsigned short)(u >> 16);
}

__device__ __forceinline__ bf16x8 as_bf16x8(u16x8 v) {
  return __builtin_bit_cast(bf16x8, v);
}

// ---------------- W = exp(-0.5*d^2/exp(2*ls)) as bf16 -----------------------
__global__ void weights_kernel(const float* __restrict__ xz, const float* __restrict__ x,
                               const float* __restrict__ ls, unsigned short* __restrict__ W) {
  int bn = blockIdx.x;
  float xv = x[bn];
  float coef = -0.5f * __expf(-2.0f * ls[0]);
  unsigned short* Wrow = W + (size_t)bn * 1024;
  #pragma unroll
  for (int i = 0; i < 4; ++i) {
    int m = threadIdx.x + i * 256;
    float d = xv - xz[m];
    Wrow[m] = f2bf(__expf(coef * d * d));
  }
}

// ---------------- Zt[b][c][k][m] = bf16(Z[b][c][m][k]) ----------------------
__global__ void transpose_kernel(const float* __restrict__ Z, unsigned short* __restrict__ Zt) {
  __shared__ float tile[64][65];
  int bc = blockIdx.z;
  const float* Zp = Z + ((size_t)bc << 20);
  unsigned short* Ztp = Zt + ((size_t)bc << 20);
  int m0 = blockIdx.x * 64, k0 = blockIdx.y * 64;
  int tx = threadIdx.x & 63, tg = threadIdx.x >> 6;
  #pragma unroll
  for (int i = 0; i < 16; ++i) {
    int ml = tg + i * 4;
    tile[ml][tx] = Zp[(size_t)(m0 + ml) * 1024 + k0 + tx];
  }
  __syncthreads();
  int tx2 = (threadIdx.x & 31) * 2, kg = threadIdx.x >> 5;
  #pragma unroll
  for (int i = 0; i < 8; ++i) {
    int kl = kg + i * 8;
    ushort2 v;
    v.x = f2bf(tile[tx2][kl]);
    v.y = f2bf(tile[tx2 + 1][kl]);
    *(ushort2*)&Ztp[(size_t)(k0 + kl) * 1024 + m0 + tx2] = v;
  }
}

// ---------------- NT bf16 GEMM: C = A(1024xK) * B(1024xK)^T -----------------
template<bool OUT_BF16, bool A_PER_B>
__global__ __launch_bounds__(512, 2)
void gemm_nt8(const unsigned short* __restrict__ A, const unsigned short* __restrict__ B,
              unsigned short* __restrict__ Cbf, float* __restrict__ Cf) {
  extern __shared__ __align__(16) char smem[];   // 128 KB: A 2buf x 32KB @0, B @65536

  // XCD-chunked bijective swizzle (512 % 8 == 0)
  const int bid = blockIdx.x;
  const int w = ((bid & 7) << 6) + (bid >> 3);
  const int bc = w >> 4;
  const int t  = w & 15;
  const int bi = t & 3, bj = t >> 2;   // consecutive blocks share (bc,bj) B-panel

  const unsigned short* Ap = A + ((size_t)(A_PER_B ? (bc >> 3) : bc) << 20);
  const unsigned short* Bp = B + ((size_t)bc << 20);
  const int tid = threadIdx.x;
  const int wv = tid >> 6, lane = tid & 63;
  const int wr = wv >> 2, wc = wv & 3;          // wave-tile: rows wr*128, cols wc*64
  const int la = lane & 15, ha = lane >> 4;

  f32x4 acc[8][4] = {};

  // ---- staging: half-tile (X, khalf) = 256 rows x 32k = 16 KB = 2 GLDS.
  // GLDS i covers rows [i*128,+128); wave wv rows [i*128+wv*16,+16); lane: row +lane>>2, 16B chunk lane&3.
  const unsigned short* gA0 = Ap + (size_t)(bi*256 +       wv*16 + (lane>>2)) * 1024 + (lane&3)*8;
  const unsigned short* gA1 = Ap + (size_t)(bi*256 + 128 + wv*16 + (lane>>2)) * 1024 + (lane&3)*8;
  const unsigned short* gB0 = Bp + (size_t)(bj*256 +       wv*16 + (lane>>2)) * 1024 + (lane&3)*8;
  const unsigned short* gB1 = Bp + (size_t)(bj*256 + 128 + wv*16 + (lane>>2)) * 1024 + (lane&3)*8;
  const int ldsw = wv * 1024;

  auto stageA = [&](int d, int kh, int kt) {
    const int ko = kt * 64 + kh * 32;
    char* dst = smem + d * 32768 + kh * 16384 + ldsw;
    GLDS(gA0 + ko, dst); GLDS(gA1 + ko, dst + 8192);
  };
  auto stageB = [&](int d, int kh, int kt) {
    const int ko = kt * 64 + kh * 32;
    char* dst = smem + 65536 + d * 32768 + kh * 16384 + ldsw;
    GLDS(gB0 + ko, dst); GLDS(gB1 + ko, dst + 8192);
  };

  // ---- fragment reads: A frag (mb,kh): row wr*128+mb*16+la, bytes kh_sub + ha*16
  const int abase = (wr * 128 + la) * 64 + ha * 16;
  const int bbase = 65536 + (wc * 64 + la) * 64 + ha * 16;

  u16x8 af[4], bfr[4];
  auto lda = [&](int d, int kh, int ms) {
    const char* p = smem + d * 32768 + kh * 16384 + ms * 4096 + abase;
    af[0] = *(const u16x8*)(p);
    af[1] = *(const u16x8*)(p + 1024);
    af[2] = *(const u16x8*)(p + 2048);
    af[3] = *(const u16x8*)(p + 3072);
  };
  auto ldb = [&](int d, int kh) {
    const char* p = smem + d * 32768 + kh * 16384 + bbase;
    bfr[0] = *(const u16x8*)(p);
    bfr[1] = *(const u16x8*)(p + 1024);
    bfr[2] = *(const u16x8*)(p + 2048);
    bfr[3] = *(const u16x8*)(p + 3072);
  };
  auto mfma16 = [&](int ms) {
    __builtin_amdgcn_s_setprio(1);
    #pragma unroll
    for (int i = 0; i < 4; ++i)
      #pragma unroll
      for (int n = 0; n < 4; ++n)
        acc[ms * 4 + i][n] = __builtin_amdgcn_mfma_f32_16x16x32_bf16(
            as_bf16x8(af[i]), as_bf16x8(bfr[n]), acc[ms * 4 + i][n], 0, 0, 0);
    __builtin_amdgcn_s_setprio(0);
  };

  // prologue: tiles 0 (both k-halves) + tile 1 k-half 0 in flight
  stageA(0, 0, 0); stageB(0, 0, 0);
  stageA(0, 1, 0); stageB(0, 1, 0);
  stageA(1, 0, 1); stageB(1, 0, 1);
  asm volatile("s_waitcnt vmcnt(8)" ::: "memory");   // tile0 khalf0 landed
  BAR();

  for (int tt = 0; tt < 16; ++tt) {
    const int d = tt & 1;
    // q0: (ms0, kh0)
    if (tt < 15) stageA(d ^ 1, 1, tt + 1);
    ldb(d, 0); lda(d, 0, 0);
    BAR();
    mfma16(0);
    BAR();
    // q1: (ms1, kh0)
    if (tt < 15) stageB(d ^ 1, 1, tt + 1);
    lda(d, 0, 1);
    BAR();
    mfma16(1);
    if (tt < 15) { asm volatile("s_waitcnt vmcnt(8)" ::: "memory"); }
    else         { asm volatile("s_waitcnt vmcnt(0)" ::: "memory"); }
    BAR();
    // q2: (ms0, kh1)
    if (tt < 14) stageA(d, 0, tt + 2);
    ldb(d, 1); lda(d, 1, 0);
    BAR();
    mfma16(0);
    BAR();
    // q3: (ms1, kh1)
    if (tt < 14) stageB(d, 0, tt + 2);
    lda(d, 1, 1);
    BAR();
    mfma16(1);
    if (tt < 14)       { asm volatile("s_waitcnt vmcnt(8)" ::: "memory"); }
    else if (tt == 14) { asm volatile("s_waitcnt vmcnt(4)" ::: "memory"); }
    BAR();
  }

  const size_t cb20 = (size_t)bc << 20;

  if (OUT_BF16) {
    // per-wave repack tile [16][72] ush (pad-72 -> <=2-way banks), 16B stores
    unsigned short* sE = (unsigned short*)(smem) + wv * 1152;   // 2304 B/wave
    const int r2 = lane >> 2, ch = lane & 3;
    #pragma unroll
    for (int mb = 0; mb < 8; ++mb) {
      #pragma unroll
      for (int nb = 0; nb < 4; ++nb)
        #pragma unroll
        for (int j = 0; j < 4; ++j)
          sE[(ha * 4 + j) * 72 + nb * 16 + la] = f2bf(acc[mb][nb][j]);
      u16x8 v0 = *(const u16x8*)&sE[r2 * 72 + ch * 16];
      u16x8 v1 = *(const u16x8*)&sE[r2 * 72 + ch * 16 + 8];
      unsigned short* gp = Cbf + cb20 +
          (size_t)(bi * 256 + wr * 128 + mb * 16 + r2) * 1024 + bj * 256 + wc * 64 + ch * 16;
      *(u16x8*)gp = v0;
      *(u16x8*)(gp + 8) = v1;
    }
  } else {
    // direct f32 stores (64B contiguous per 16-lane group)
    #pragma unroll
    for (int mb = 0; mb < 8; ++mb) {
      #pragma unroll
      for (int nb = 0; nb < 4; ++nb) {
        const int col = bj * 256 + wc * 64 + nb * 16 + la;
        #pragma unroll
        for (int j = 0; j < 4; ++j) {
          const int row = bi * 256 + wr * 128 + mb * 16 + ha * 4 + j;
          Cf[cb20 + (size_t)row * 1024 + col] = acc[mb][nb][j];
        }
      }
    }
  }
}

extern "C" void kernel_launch(void* const* d_in, const int* in_sizes, int n_in,
                              void* d_out, int out_size, void* d_ws, size_t ws_size,
                              hipStream_t stream) {
  const float* xz = (const float*)d_in[0];
  const float* z  = (const float*)d_in[1];
  const float* x  = (const float*)d_in[2];
  const float* ls = (const float*)d_in[3];
  float* out = (float*)d_out;

  unsigned short* W  = (unsigned short*)d_ws;          // 8 MB
  unsigned short* Zt = W + ((size_t)4 << 20);          // 64 MB
  unsigned short* z1 = Zt + ((size_t)32 << 20);        // 64 MB

  // allow 128 KB dynamic LDS (idempotent host-side calls; not stream ops)
  hipFuncSetAttribute((const void*)gemm_nt8<true,  true >,
                      hipFuncAttributeMaxDynamicSharedMemorySize, 131072);
  hipFuncSetAttribute((const void*)gemm_nt8<false, false>,
                      hipFuncAttributeMaxDynamicSharedMemorySize, 131072);

  hipMemcpyAsync(out, xz, 1024 * sizeof(float), hipMemcpyDeviceToDevice, stream);
  weights_kernel<<<4096, 256, 0, stream>>>(xz, x, ls, W);
  transpose_kernel<<<dim3(16, 16, 32), 256, 0, stream>>>(z, Zt);
  gemm_nt8<true,  true ><<<512, 512, 131072, stream>>>(W,  Zt, z1, nullptr);
  gemm_nt8<false, false><<<512, 512, 131072, stream>>>(z1, z1, nullptr, out + 1024);
}